// Round 8
// baseline (544.758 us; speedup 1.0000x reference)
//
#include <hip/hip_runtime.h>
#include <hip/hip_bf16.h>
#include <cmath>

// ---------------------------------------------------------------------------
// GAT 2-layer forward.
//  - LDS-free MFMA GEMMs (A direct global->reg, B pre-transposed bf16).
//  - scores1 fused into GEMM1 (extra 16 output cols via Wa = W1 @ blockdiag(a)).
//  - h1 stored INT8 per-row-scaled; (score,scale) pairs in dense float2 table
//    -> agg1 does 2 gathers/edge (pair + 8B values).
//  - h2 stored as 64B NODE RECORDS: 40 int8 + pads + {score_src, scale} f32
//    -> agg2 gathers exactly ONE line per edge.
//  - Inline-softmax aggregation, depth-3 software pipelines.
//  - CSR counting sort; self-loops placed during scan; 2 dst-ranged scatters.
//  - log_softmax fused into agg2.
// ---------------------------------------------------------------------------

#define LEAKY(e) ((e) >= 0.f ? (e) : 0.2f * (e))

typedef unsigned short ushortT;
typedef unsigned int uintT;
typedef unsigned char ucharT;
typedef __attribute__((ext_vector_type(8))) short short8;
typedef __attribute__((ext_vector_type(4))) float float4v;

static __device__ __forceinline__ float bflo(uintT u) {
    return __uint_as_float(u << 16);
}
static __device__ __forceinline__ float bfhi(uintT u) {
    return __uint_as_float(u & 0xffff0000u);
}
static __device__ __forceinline__ ushortT f2bf(float f) {
    __hip_bfloat16 h = __float2bfloat16(f);   // RNE
    return *reinterpret_cast<ushortT*>(&h);
}
static __device__ __forceinline__ uintT pk(float a, float b) {
    return (uintT)f2bf(a) | ((uintT)f2bf(b) << 16);
}
static __device__ __forceinline__ float sb(uintT u, int k) {   // signed byte k
    return (float)((int)(u << (24 - 8 * k)) >> 24);
}

// ---------------- prep: transpose weights to bf16 + score matrix -----------
// W1t rows 0..255: storage row s=j*16+n holds W1 col (16n+j) [permuted tiling]
// W1t rows 256..271: Wa (scores);  W2t: 48 x 256 (cols 40..47 zero)
__global__ __launch_bounds__(256) void k_prep(const float* __restrict__ W1,
                                              const float* __restrict__ W2,
                                              const float* __restrict__ a1s,
                                              const float* __restrict__ a1d,
                                              ushortT* __restrict__ W1t,
                                              ushortT* __restrict__ W2t) {
    int t = blockIdx.x * 256 + threadIdx.x;
    if (t < 128 * 256) {
        int k = t >> 8, s = t & 255;
        int c = ((s & 15) << 4) | (s >> 4);
        W1t[s * 128 + k] = f2bf(W1[(size_t)k * 256 + c]);
    } else if (t < 128 * 256 + 48 * 256) {
        int q = t - 128 * 256;
        int k = q / 48, c = q - k * 48;
        W2t[c * 256 + k] = (c < 40) ? f2bf(W2[k * 40 + c]) : (ushortT)0;
    } else if (t < 128 * 256 + 48 * 256 + 2048) {
        int q = t - (128 * 256 + 48 * 256);
        int k = q >> 4, j = q & 15;
        int h = j & 7;
        const float* av = ((j < 8) ? a1s : a1d) + h * 32;
        const float* wr = W1 + (size_t)k * 256 + h * 32;
        float s = 0.f;
        #pragma unroll
        for (int c = 0; c < 32; ++c) s += wr[c] * av[c];
        W1t[(256 + j) * 128 + k] = f2bf(s);
    }
}

// ---------------- GEMM1: x[M,128] @ W1 -> int8 h1i + spk pairs + s1d -------
__global__ __launch_bounds__(256) void k_gemm1(const float* __restrict__ A,
                                               const ushortT* __restrict__ Bt,
                                               ucharT* __restrict__ h1i,
                                               float2* __restrict__ spk,
                                               float* __restrict__ s1d, int M) {
    int lane = threadIdx.x & 63, wave = threadIdx.x >> 6;
    int slab = blockIdx.x * 4 + wave;
    int r0 = slab * 16;
    if (r0 >= M) return;
    int n = lane & 15, q = lane >> 4;
    const float* arow = A + (size_t)(r0 + n) * 128 + q * 8;
    short8 af[4];
    #pragma unroll
    for (int s = 0; s < 4; ++s) {
        float4 v0 = *(const float4*)(arow + s * 32);
        float4 v1 = *(const float4*)(arow + s * 32 + 4);
        short8 a;
        a[0] = (short)f2bf(v0.x); a[1] = (short)f2bf(v0.y);
        a[2] = (short)f2bf(v0.z); a[3] = (short)f2bf(v0.w);
        a[4] = (short)f2bf(v1.x); a[5] = (short)f2bf(v1.y);
        a[6] = (short)f2bf(v1.z); a[7] = (short)f2bf(v1.w);
        af[s] = a;
    }
    float4v acc[17];
    #pragma unroll
    for (int j = 0; j < 17; ++j) acc[j] = (float4v){0.f, 0.f, 0.f, 0.f};
    #pragma unroll
    for (int s = 0; s < 4; ++s) {
        #pragma unroll
        for (int j = 0; j < 17; ++j) {
            short8 b = *(const short8*)(Bt + (size_t)(j * 16 + n) * 128 + s * 32 + q * 8);
            acc[j] = __builtin_amdgcn_mfma_f32_16x16x32_bf16(af[s], b, acc[j], 0, 0, 0);
        }
    }
    // acc[j][r] = value for row (r0+q*4+r), ORIGINAL col (16n + j)
    float am[4];
    #pragma unroll
    for (int r = 0; r < 4; ++r) {
        float m = 0.f;
        #pragma unroll
        for (int j = 0; j < 16; ++j) m = fmaxf(m, fabsf(acc[j][r]));
        am[r] = m;
    }
    #pragma unroll
    for (int off = 1; off < 16; off <<= 1) {
        #pragma unroll
        for (int r = 0; r < 4; ++r) am[r] = fmaxf(am[r], __shfl_xor(am[r], off, 64));
    }
    #pragma unroll
    for (int r = 0; r < 4; ++r) {
        int row = r0 + q * 4 + r;
        float m = am[r];
        float si = (m > 0.f) ? 127.f / m : 0.f;
        uintT wd[4];
        #pragma unroll
        for (int wq = 0; wq < 4; ++wq) {
            uintT p4 = 0;
            #pragma unroll
            for (int b = 0; b < 4; ++b) {
                int j = wq * 4 + b;
                int qv = (int)rintf(acc[j][r] * si);
                p4 |= ((uintT)(qv & 0xff)) << (8 * b);
            }
            wd[wq] = p4;
        }
        uint4 o = make_uint4(wd[0], wd[1], wd[2], wd[3]);
        *(uint4*)(h1i + (size_t)row * 256 + n * 16) = o;
        float vv = acc[16][r];
        if (n < 8) spk[(size_t)row * 8 + n] = make_float2(vv, m * (1.f / 127.f));
        else       s1d[(size_t)row * 8 + (n - 8)] = vv;
    }
}

// ---------------- CSR build ------------------------------------------------
__global__ __launch_bounds__(256) void k_deg(const int* __restrict__ ei, int E,
                                             int* __restrict__ deg) {
    int e4 = (blockIdx.x * 256 + threadIdx.x) * 4;
    if (e4 + 3 < E) {
        int4 d = *(const int4*)(ei + E + e4);
        atomicAdd(&deg[d.x], 1);
        atomicAdd(&deg[d.y], 1);
        atomicAdd(&deg[d.z], 1);
        atomicAdd(&deg[d.w], 1);
    } else {
        for (int e = e4; e < E; ++e) atomicAdd(&deg[ei[E + e]], 1);
    }
}

__global__ __launch_bounds__(1024) void k_scan_a(const int* __restrict__ deg,
                                                 int* __restrict__ tmp,
                                                 int* __restrict__ part, int n) {
    __shared__ int wsum[16];
    int t = threadIdx.x, lane = t & 63, wv = t >> 6;
    int i = blockIdx.x * 1024 + t;
    int v = (i < n) ? (deg[i] + 1) : 0;   // +1 = self loop
    int incl = v;
    #pragma unroll
    for (int off = 1; off < 64; off <<= 1) {
        int u = __shfl_up(incl, off, 64);
        if (lane >= off) incl += u;
    }
    if (lane == 63) wsum[wv] = incl;
    __syncthreads();
    if (wv == 0) {
        int s = (lane < 16) ? wsum[lane] : 0;
        #pragma unroll
        for (int off = 1; off < 16; off <<= 1) {
            int u = __shfl_up(s, off, 64);
            if (lane >= off) s += u;
        }
        if (lane < 16) wsum[lane] = s;
    }
    __syncthreads();
    int g = incl + (wv ? wsum[wv - 1] : 0);
    if (i < n) tmp[i] = g;
    if (t == 1023) part[blockIdx.x] = g;
}

__global__ __launch_bounds__(1024) void k_scan_b(int* __restrict__ part, int nb) {
    __shared__ int wsum[16];
    int t = threadIdx.x, lane = t & 63, wv = t >> 6;
    int v = (t < nb) ? part[t] : 0;
    int incl = v;
    #pragma unroll
    for (int off = 1; off < 64; off <<= 1) {
        int u = __shfl_up(incl, off, 64);
        if (lane >= off) incl += u;
    }
    if (lane == 63) wsum[wv] = incl;
    __syncthreads();
    if (wv == 0) {
        int s = (lane < 16) ? wsum[lane] : 0;
        #pragma unroll
        for (int off = 1; off < 16; off <<= 1) {
            int u = __shfl_up(s, off, 64);
            if (lane >= off) s += u;
        }
        if (lane < 16) wsum[lane] = s;
    }
    __syncthreads();
    int g = incl + (wv ? wsum[wv - 1] : 0);
    if (t < nb) part[t] = g;
}

__global__ __launch_bounds__(256) void k_scan_c(const int* __restrict__ deg,
                                                const int* __restrict__ tmp,
                                                const int* __restrict__ part,
                                                int* __restrict__ rowptr,
                                                int* __restrict__ cursor,
                                                int* __restrict__ csr_src, int n) {
    int i = blockIdx.x * blockDim.x + threadIdx.x;
    if (i >= n) return;
    int b = i >> 10;
    int off = b ? part[b - 1] : 0;
    int incl = tmp[i] + off;
    rowptr[i + 1] = incl;
    int start = incl - (deg[i] + 1);
    csr_src[start] = i;        // self loop pre-placed
    cursor[i] = start + 1;
    if (i == 0) rowptr[0] = 0;
}

__global__ __launch_bounds__(256) void k_scatter_r(const int* __restrict__ ei, int E,
                                                   int* __restrict__ cursor,
                                                   int* __restrict__ csr_src,
                                                   int lo, int hi) {
    int e = blockIdx.x * blockDim.x + threadIdx.x;
    if (e >= E) return;
    int dst = ei[E + e];
    if (dst < lo || dst >= hi) return;
    int pos = atomicAdd(&cursor[dst], 1);
    csr_src[pos] = ei[e];
}

// ---------------- layer-1 aggregation: int8 values, 2 slots x depth-3 ------
__global__ __launch_bounds__(256) void k_agg1(const ucharT* __restrict__ h1i,
                                              const float2* __restrict__ spk,
                                              const float* __restrict__ sdst,
                                              const int* __restrict__ rowptr,
                                              const int* __restrict__ csr_src,
                                              const float* __restrict__ b1,
                                              ushortT* __restrict__ out1, int N) {
    int lane = threadIdx.x & 63;
    int wid = threadIdx.x >> 6;
    int n = blockIdx.x * 4 + wid;
    if (n >= N) return;
    int slot = lane >> 5;        // edge parity
    int cl = lane & 31;          // 8 channels each (int8)
    int head = cl >> 2;
    int beg = rowptr[n], end = rowptr[n + 1];
    float sdn = sdst[(size_t)n * 8 + head];
    const ucharT* hb = h1i + cl * 8;
    float a0 = 0.f, a1 = 0.f, a2 = 0.f, a3 = 0.f;
    float a4 = 0.f, a5 = 0.f, a6 = 0.f, a7 = 0.f, l = 0.f;
    int i0 = beg + slot;
    float2 sp0 = make_float2(0.f, 0.f), sp1 = sp0, sp2 = sp0;
    uint2 v0 = make_uint2(0u, 0u), v1 = v0, v2 = v0;
    if (i0 < end) {
        int s = csr_src[i0];
        sp0 = spk[(size_t)s * 8 + head];
        v0 = *(const uint2*)(hb + (size_t)s * 256);
    }
    if (i0 + 2 < end) {
        int s = csr_src[i0 + 2];
        sp1 = spk[(size_t)s * 8 + head];
        v1 = *(const uint2*)(hb + (size_t)s * 256);
    }
    if (i0 + 4 < end) {
        int s = csr_src[i0 + 4];
        sp2 = spk[(size_t)s * 8 + head];
        v2 = *(const uint2*)(hb + (size_t)s * 256);
    }
    for (int idx = i0; idx < end; idx += 2) {
        float2 sp = sp0; uint2 v = v0;
        sp0 = sp1; v0 = v1;
        sp1 = sp2; v1 = v2;
        int i6 = idx + 6;
        if (i6 < end) {
            int s = csr_src[i6];
            sp2 = spk[(size_t)s * 8 + head];
            v2 = *(const uint2*)(hb + (size_t)s * 256);
        }
        float p = __expf(LEAKY(sp.x + sdn));
        l += p;
        float ps = p * sp.y;
        a0 += ps * sb(v.x, 0); a1 += ps * sb(v.x, 1);
        a2 += ps * sb(v.x, 2); a3 += ps * sb(v.x, 3);
        a4 += ps * sb(v.y, 0); a5 += ps * sb(v.y, 1);
        a6 += ps * sb(v.y, 2); a7 += ps * sb(v.y, 3);
    }
    a0 += __shfl_xor(a0, 32, 64); a1 += __shfl_xor(a1, 32, 64);
    a2 += __shfl_xor(a2, 32, 64); a3 += __shfl_xor(a3, 32, 64);
    a4 += __shfl_xor(a4, 32, 64); a5 += __shfl_xor(a5, 32, 64);
    a6 += __shfl_xor(a6, 32, 64); a7 += __shfl_xor(a7, 32, 64);
    l += __shfl_xor(l, 32, 64);
    if (slot == 0) {
        float inv = 1.f / l;
        const float4 bb0 = *(const float4*)(b1 + cl * 8);
        const float4 bb1 = *(const float4*)(b1 + cl * 8 + 4);
        uint4 o;
        o.x = pk(fmaxf(a0 * inv + bb0.x, 0.f), fmaxf(a1 * inv + bb0.y, 0.f));
        o.y = pk(fmaxf(a2 * inv + bb0.z, 0.f), fmaxf(a3 * inv + bb0.w, 0.f));
        o.z = pk(fmaxf(a4 * inv + bb1.x, 0.f), fmaxf(a5 * inv + bb1.y, 0.f));
        o.w = pk(fmaxf(a6 * inv + bb1.z, 0.f), fmaxf(a7 * inv + bb1.w, 0.f));
        *(uint4*)(out1 + (size_t)n * 256 + cl * 8) = o;
    }
}

// ---------------- GEMM2: out1b @ W2 -> 64B int8 node records + s2d ---------
// record: [0..39] int8 vals, [40..47] pad, [48] score_src f32, [52] scale f32
__global__ __launch_bounds__(256) void k_gemm2(const ushortT* __restrict__ X,
                                               const ushortT* __restrict__ Bt,
                                               const float* __restrict__ a2s,
                                               const float* __restrict__ a2d,
                                               ucharT* __restrict__ h2r,
                                               float* __restrict__ s2d, int M) {
    int lane = threadIdx.x & 63, wave = threadIdx.x >> 6;
    int slab = blockIdx.x * 4 + wave;
    int r0 = slab * 16;
    if (r0 >= M) return;
    int n = lane & 15, q = lane >> 4;
    const ushortT* xrow = X + (size_t)(r0 + n) * 256 + q * 8;
    float4v acc[3];
    #pragma unroll
    for (int j = 0; j < 3; ++j) acc[j] = (float4v){0.f, 0.f, 0.f, 0.f};
    #pragma unroll
    for (int s = 0; s < 8; ++s) {
        short8 a = *(const short8*)(xrow + s * 32);
        #pragma unroll
        for (int j = 0; j < 3; ++j) {
            short8 b = *(const short8*)(Bt + (size_t)(j * 16 + n) * 256 + s * 32 + q * 8);
            acc[j] = __builtin_amdgcn_mfma_f32_16x16x32_bf16(a, b, acc[j], 0, 0, 0);
        }
    }
    float asv[3], adv[3];
    #pragma unroll
    for (int j = 0; j < 3; ++j) {
        int col = j * 16 + n;
        asv[j] = (col < 40) ? a2s[col] : 0.f;
        adv[j] = (col < 40) ? a2d[col] : 0.f;
    }
    float us[4], ud[4], am[4];
    #pragma unroll
    for (int r = 0; r < 4; ++r) {
        us[r] = acc[0][r] * asv[0] + acc[1][r] * asv[1] + acc[2][r] * asv[2];
        ud[r] = acc[0][r] * adv[0] + acc[1][r] * adv[1] + acc[2][r] * adv[2];
        am[r] = fmaxf(fmaxf(fabsf(acc[0][r]), fabsf(acc[1][r])), fabsf(acc[2][r]));
    }
    #pragma unroll
    for (int off = 1; off < 16; off <<= 1) {
        #pragma unroll
        for (int r = 0; r < 4; ++r) {
            us[r] += __shfl_xor(us[r], off, 64);
            ud[r] += __shfl_xor(ud[r], off, 64);
            am[r] = fmaxf(am[r], __shfl_xor(am[r], off, 64));
        }
    }
    #pragma unroll
    for (int r = 0; r < 4; ++r) {
        int row = r0 + q * 4 + r;
        ucharT* rec = h2r + (size_t)row * 64;
        float m = am[r];
        float si = (m > 0.f) ? 127.f / m : 0.f;
        #pragma unroll
        for (int j = 0; j < 3; ++j) {
            int col = j * 16 + n;
            if (col < 40) {
                int qv = (int)rintf(acc[j][r] * si);
                rec[col] = (ucharT)(qv & 0xff);
            }
        }
        if (n == 0) {
            *(float2*)(rec + 48) = make_float2(us[r], m * (1.f / 127.f));
            s2d[row] = ud[r];
        }
    }
}

// ---------------- layer-2 aggregation + log_softmax (1-line records) -------
__global__ __launch_bounds__(256) void k_agg2lsm(const ucharT* __restrict__ h2r,
                                                 const float* __restrict__ sd,
                                                 const int* __restrict__ rowptr,
                                                 const int* __restrict__ csr_src,
                                                 const float* __restrict__ b2,
                                                 float* __restrict__ out, int N) {
    int lane = threadIdx.x & 63;
    int wid = threadIdx.x >> 6;
    int n = blockIdx.x * 4 + wid;
    if (n >= N) return;
    int el = lane / 10;
    int cl = lane - el * 10;
    int beg = rowptr[n], end = rowptr[n + 1];
    float sdn = sd[n];
    float a0 = 0.f, a1 = 0.f, a2 = 0.f, a3 = 0.f, l = 0.f;
    if (el < 6) {
        int ia = beg + el;
        float2 sp0 = make_float2(0.f, 0.f), sp1 = sp0, sp2 = sp0;
        uintT v0 = 0u, v1 = 0u, v2 = 0u;
        if (ia < end) {
            const ucharT* rec = h2r + (size_t)csr_src[ia] * 64;
            v0 = *(const uintT*)(rec + cl * 4);
            sp0 = *(const float2*)(rec + 48);
        }
        if (ia + 6 < end) {
            const ucharT* rec = h2r + (size_t)csr_src[ia + 6] * 64;
            v1 = *(const uintT*)(rec + cl * 4);
            sp1 = *(const float2*)(rec + 48);
        }
        if (ia + 12 < end) {
            const ucharT* rec = h2r + (size_t)csr_src[ia + 12] * 64;
            v2 = *(const uintT*)(rec + cl * 4);
            sp2 = *(const float2*)(rec + 48);
        }
        for (int idx = ia; idx < end; idx += 6) {
            float2 sp = sp0; uintT v = v0;
            sp0 = sp1; v0 = v1;
            sp1 = sp2; v1 = v2;
            int i3 = idx + 18;
            if (i3 < end) {
                const ucharT* rec = h2r + (size_t)csr_src[i3] * 64;
                v2 = *(const uintT*)(rec + cl * 4);
                sp2 = *(const float2*)(rec + 48);
            }
            float p = __expf(LEAKY(sp.x + sdn));
            l += p;
            float ps = p * sp.y;
            a0 += ps * sb(v, 0); a1 += ps * sb(v, 1);
            a2 += ps * sb(v, 2); a3 += ps * sb(v, 3);
        }
    }
    // reduce the 6 slots into lanes 0..9
    float t0 = 0.f, t1 = 0.f, t2 = 0.f, t3 = 0.f, lt = 0.f;
    #pragma unroll
    for (int k = 0; k < 6; ++k) {
        int sl = cl + 10 * k;
        t0 += __shfl(a0, sl, 64);
        t1 += __shfl(a1, sl, 64);
        t2 += __shfl(a2, sl, 64);
        t3 += __shfl(a3, sl, 64);
        if (cl == 0) lt += __shfl(l, sl, 64);
    }
    lt = __shfl(lt, 0, 64);
    float inv = 1.f / lt;
    float o0 = t0 * inv + b2[cl * 4 + 0];
    float o1 = t1 * inv + b2[cl * 4 + 1];
    float o2 = t2 * inv + b2[cl * 4 + 2];
    float o3 = t3 * inv + b2[cl * 4 + 3];
    float lm = (lane < 10) ? fmaxf(fmaxf(o0, o1), fmaxf(o2, o3)) : -INFINITY;
    #pragma unroll
    for (int off = 32; off; off >>= 1) lm = fmaxf(lm, __shfl_xor(lm, off, 64));
    float le = (lane < 10)
        ? __expf(o0 - lm) + __expf(o1 - lm) + __expf(o2 - lm) + __expf(o3 - lm)
        : 0.f;
    #pragma unroll
    for (int off = 32; off; off >>= 1) le += __shfl_xor(le, off, 64);
    float ls = lm + logf(le);
    if (lane < 10) {
        float4 w = make_float4(o0 - ls, o1 - ls, o2 - ls, o3 - ls);
        *(float4*)(out + (size_t)n * 40 + cl * 4) = w;
    }
}

// ---------------------------------------------------------------------------
extern "C" void kernel_launch(void* const* d_in, const int* in_sizes, int n_in,
                              void* d_out, int out_size, void* d_ws, size_t ws_size,
                              hipStream_t stream) {
    const float* x   = (const float*)d_in[0];
    const int*   ei  = (const int*)d_in[1];
    const float* W1  = (const float*)d_in[2];
    const float* a1s = (const float*)d_in[3];
    const float* a1d = (const float*)d_in[4];
    const float* b1  = (const float*)d_in[5];
    const float* W2  = (const float*)d_in[6];
    const float* a2s = (const float*)d_in[7];
    const float* a2d = (const float*)d_in[8];
    const float* b2  = (const float*)d_in[9];
    float* out = (float*)d_out;

    const int N = in_sizes[0] / 128;   // 100000
    const int E = in_sizes[1] / 2;     // 1600000
    const int ET = E + N;

    // ---- workspace layout ----
    char* w = (char*)d_ws;
    ucharT* h1i = (ucharT*)w;                             // N*256 int8 (25.6 MB)
    float2* spk = (float2*)(w + (size_t)N * 256);         // N*8 float2 (6.4 MB)
    ushortT* out1b = (ushortT*)(w + (size_t)N * 256 + (size_t)N * 64);  // N*256 bf16
    float* s1d  = (float*)(out1b + (size_t)N * 256);      // N*8
    int* i_deg = (int*)(s1d + (size_t)N * 8);
    int* i_row = i_deg + (N + 16);
    int* i_cur = i_row + (N + 16);
    int* i_tmp = i_cur + (N + 16);
    int* i_par = i_tmp + (N + 16);
    int* i_csr = i_par + 2048;                            // ET ints
    ushortT* W1t = (ushortT*)(i_csr + ET);                // 272*128 bf16
    ushortT* W2t = W1t + 272 * 128;                       // 48*256 bf16
    // layer-2 overlays h1i (dead after k_agg1)
    ucharT* h2r = (ucharT*)w;                             // N*64 records (6.4 MB)
    float* s2d  = (float*)(w + (size_t)N * 64);           // N

    const int nb4 = (N + 3) / 4;
    const int nbs = (N + 1023) / 1024;
    const int nbG = (N / 16 + 3) / 4;   // gemm blocks (4 waves x 16 rows)

    // ---- CSR build ----
    hipMemsetAsync(i_deg, 0, (size_t)N * sizeof(int), stream);
    k_deg<<<(E / 4 + 255) / 256, 256, 0, stream>>>(ei, E, i_deg);
    k_scan_a<<<nbs, 1024, 0, stream>>>(i_deg, i_tmp, i_par, N);
    k_scan_b<<<1, 1024, 0, stream>>>(i_par, nbs);
    k_scan_c<<<(N + 255) / 256, 256, 0, stream>>>(i_deg, i_tmp, i_par, i_row, i_cur, i_csr, N);
    {   // 2 dst-ranged scatter passes (write window ~3.4 MB each)
        int step = (N + 1) / 2;
        k_scatter_r<<<(E + 255) / 256, 256, 0, stream>>>(ei, E, i_cur, i_csr, 0, step);
        k_scatter_r<<<(E + 255) / 256, 256, 0, stream>>>(ei, E, i_cur, i_csr, step, N);
    }

    // ---- weight prep ----
    k_prep<<<184, 256, 0, stream>>>(W1, W2, a1s, a1d, W1t, W2t);

    // ---- layer 1 ----
    k_gemm1<<<nbG, 256, 0, stream>>>(x, W1t, h1i, spk, s1d, N);
    k_agg1<<<nb4, 256, 0, stream>>>(h1i, spk, s1d, i_row, i_csr, b1, out1b, N);

    // ---- layer 2 ----
    k_gemm2<<<nbG, 256, 0, stream>>>(out1b, W2t, a2s, a2d, h2r, s2d, N);
    k_agg2lsm<<<nb4, 256, 0, stream>>>(h2r, s2d, i_row, i_csr, b2, out, N);
}